// Round 5
// baseline (84.837 us; speedup 1.0000x reference)
//
#include <hip/hip_runtime.h>
#include <math.h>

#define BATCH 16384
#define OUTF  1024
#define INF   1024
#define KPROJ 256
#define MTOT  (BATCH + OUTF)   // 17408

#define NZ_THRESH 0.15f        // ~6.8 sigma of f16 dot error (sigma ~0.022)

typedef unsigned long long u64;
typedef unsigned short     u16;
typedef _Float16           f16;
typedef __attribute__((ext_vector_type(8))) _Float16 f16x8;
typedef __attribute__((ext_vector_type(4))) float    f32x4;

#define SCHED0() __builtin_amdgcn_sched_barrier(0)

// ---------------------------------------------------------------------------
// prep_p: P (256 x 1024) fp32 -> f16 in MFMA FRAGMENT ORDER, coalesced.
// Fragment f = (kt*16 + j)*2 + ks holds, for lane = lq*16+l15, the 8 f16
// elements  B[col = j*16+l15][k = kt*64 + ks*32 + lq*8 .. +7].
// Block j handles cols j*16..j*16+15: reads 16 P-rows fully coalesced
// (one float4 per thread per row), converts into an LDS tile, then writes
// 32 fragments as wave-contiguous 1KB bursts.
// ---------------------------------------------------------------------------
__global__ __launch_bounds__(256) void prep_p(const float* __restrict__ P,
                                              f16* __restrict__ Bf) {
    __shared__ f16 tile[16][1024];     // 32 KB
    const int j = blockIdx.x;          // 0..15 (col block)
    const int t = threadIdx.x;
#pragma unroll
    for (int r = 0; r < 16; ++r) {
        const float4 f = ((const float4*)(P + (size_t)(j * 16 + r) * INF))[t];
        f16* d = &tile[r][t * 4];
        d[0] = (f16)f.x; d[1] = (f16)f.y; d[2] = (f16)f.z; d[3] = (f16)f.w;
    }
    __syncthreads();
    const int lane = t & 63, fo = t >> 6;
    const int lq = lane >> 4, l15 = lane & 15;
#pragma unroll
    for (int g = 0; g < 8; ++g) {
        const int f  = g * 4 + fo;         // 0..31 = kt*2 + ks
        const int kt = f >> 1, ks = f & 1;
        f16x8 h = *(const f16x8*)&tile[l15][kt * 64 + ks * 32 + lq * 8];
        *(f16x8*)(Bf + (size_t)((((kt * 16 + j) * 2 + ks) * 64) + lane) * 8) = h;
    }
}

// ---------------------------------------------------------------------------
// K-split sign GEMM, R4 structure + NON-TEMPORAL A stream.
// The A stream (68 MB read-once) previously swept ~8.5 MB/XCD through the
// 4 MB L2, evicting the 512 KB Bf working set -> B-fragment loads serviced
// from Infinity Cache (~700 cyc) every K-step in every prior structure.
// All A loads now carry the nt flag (no L2 allocate), so Bf stays L2-hot.
// Everything else identical to R4: wave w owns K-quarter ((w+blk)&3)*4,
// column rotation roff=(blk*5)&15, 16 unrolled batches, 3 rotating register
// buffer sets, counted s_waitcnt vmcnt(16) (24 B-loads in flight).
// ---------------------------------------------------------------------------
__global__ __launch_bounds__(256, 2) void gemm_signs(const float* __restrict__ X,
                                                     const float* __restrict__ W,
                                                     const f16* __restrict__ Bf,
                                                     const float* __restrict__ Pf,
                                                     u64* __restrict__ cx,
                                                     u64* __restrict__ cw,
                                                     float* __restrict__ xn,
                                                     float* __restrict__ wn) {
    __shared__ f32x4 red[2][16][64];    // 32 KB reduction buffer
    __shared__ float nsq[4][16];
    __shared__ u16 sw[16][16];

    const int t    = threadIdx.x;
    const int wid  = t >> 6, lane = t & 63;
    const int l4   = lane >> 4, l15 = lane & 15;
    const int row0 = blockIdx.x * 16;
    const int kb   = ((wid + blockIdx.x) & 3) * 4;   // K-quarter rotation
    const int roff = (blockIdx.x * 5) & 15;          // column rotation

    const float* Asrc = (row0 < BATCH) ? X + (size_t)row0 * INF
                                       : W + (size_t)(row0 - BATCH) * INF;
    const float* aPtr = Asrc + (size_t)l15 * INF + l4 * 8;

    // ---- A preload: this wave's 4 K-tiles, fp32 -> f16 fragments (nt) ----
    f16x8 af[8];            // af[2i]: ks=0 of tile kb+i, af[2i+1]: ks=1
    float ssq = 0.0f;
#pragma unroll
    for (int i = 0; i < 4; ++i) {
        const float* p = aPtr + (kb + i) * 64;
        f32x4 q0 = __builtin_nontemporal_load((const f32x4*)(p));
        f32x4 q1 = __builtin_nontemporal_load((const f32x4*)(p + 4));
        f32x4 q2 = __builtin_nontemporal_load((const f32x4*)(p + 32));
        f32x4 q3 = __builtin_nontemporal_load((const f32x4*)(p + 36));
        ssq += q0[0] * q0[0] + q0[1] * q0[1] + q0[2] * q0[2] + q0[3] * q0[3] +
               q1[0] * q1[0] + q1[1] * q1[1] + q1[2] * q1[2] + q1[3] * q1[3] +
               q2[0] * q2[0] + q2[1] * q2[1] + q2[2] * q2[2] + q2[3] * q2[3] +
               q3[0] * q3[0] + q3[1] * q3[1] + q3[2] * q3[2] + q3[3] * q3[3];
        f16x8 a0, a1;
        a0[0] = (f16)q0[0]; a0[1] = (f16)q0[1]; a0[2] = (f16)q0[2]; a0[3] = (f16)q0[3];
        a0[4] = (f16)q1[0]; a0[5] = (f16)q1[1]; a0[6] = (f16)q1[2]; a0[7] = (f16)q1[3];
        a1[0] = (f16)q2[0]; a1[1] = (f16)q2[1]; a1[2] = (f16)q2[2]; a1[3] = (f16)q2[3];
        a1[4] = (f16)q3[0]; a1[5] = (f16)q3[1]; a1[6] = (f16)q3[2]; a1[7] = (f16)q3[3];
        af[2 * i]     = a0;
        af[2 * i + 1] = a1;
    }

    // f16-element offsets of each acc slot's column fragment pair
    int joff[16];
#pragma unroll
    for (int s = 0; s < 16; ++s) joff[s] = ((s + roff) & 15) * 1024;

    f32x4 acc[16] = {};
    const f16* bq = Bf + lane * 8;

    f16x8 bA0, bA1, bA2, bA3, bA4, bA5, bA6, bA7;
    f16x8 bB0, bB1, bB2, bB3, bB4, bB5, bB6, bB7;
    f16x8 bC0, bC1, bC2, bC3, bC4, bC5, bC6, bC7;

#define BLOAD(BUF, G)                                                         \
    {                                                                         \
        const f16* bt_ = bq + (size_t)(kb + ((G) >> 2)) * 16384;              \
        BUF##0 = *(const f16x8*)(bt_ + joff[((G) & 3) * 4 + 0]);              \
        BUF##1 = *(const f16x8*)(bt_ + joff[((G) & 3) * 4 + 0] + 512);        \
        BUF##2 = *(const f16x8*)(bt_ + joff[((G) & 3) * 4 + 1]);              \
        BUF##3 = *(const f16x8*)(bt_ + joff[((G) & 3) * 4 + 1] + 512);        \
        BUF##4 = *(const f16x8*)(bt_ + joff[((G) & 3) * 4 + 2]);              \
        BUF##5 = *(const f16x8*)(bt_ + joff[((G) & 3) * 4 + 2] + 512);        \
        BUF##6 = *(const f16x8*)(bt_ + joff[((G) & 3) * 4 + 3]);              \
        BUF##7 = *(const f16x8*)(bt_ + joff[((G) & 3) * 4 + 3] + 512);        \
    }

#define BMFMA(BUF, G)                                                         \
    {                                                                         \
        acc[((G) & 3) * 4 + 0] = __builtin_amdgcn_mfma_f32_16x16x32_f16(      \
            af[2 * ((G) >> 2)],     BUF##0, acc[((G) & 3) * 4 + 0], 0, 0, 0); \
        acc[((G) & 3) * 4 + 0] = __builtin_amdgcn_mfma_f32_16x16x32_f16(      \
            af[2 * ((G) >> 2) + 1], BUF##1, acc[((G) & 3) * 4 + 0], 0, 0, 0); \
        acc[((G) & 3) * 4 + 1] = __builtin_amdgcn_mfma_f32_16x16x32_f16(      \
            af[2 * ((G) >> 2)],     BUF##2, acc[((G) & 3) * 4 + 1], 0, 0, 0); \
        acc[((G) & 3) * 4 + 1] = __builtin_amdgcn_mfma_f32_16x16x32_f16(      \
            af[2 * ((G) >> 2) + 1], BUF##3, acc[((G) & 3) * 4 + 1], 0, 0, 0); \
        acc[((G) & 3) * 4 + 2] = __builtin_amdgcn_mfma_f32_16x16x32_f16(      \
            af[2 * ((G) >> 2)],     BUF##4, acc[((G) & 3) * 4 + 2], 0, 0, 0); \
        acc[((G) & 3) * 4 + 2] = __builtin_amdgcn_mfma_f32_16x16x32_f16(      \
            af[2 * ((G) >> 2) + 1], BUF##5, acc[((G) & 3) * 4 + 2], 0, 0, 0); \
        acc[((G) & 3) * 4 + 3] = __builtin_amdgcn_mfma_f32_16x16x32_f16(      \
            af[2 * ((G) >> 2)],     BUF##6, acc[((G) & 3) * 4 + 3], 0, 0, 0); \
        acc[((G) & 3) * 4 + 3] = __builtin_amdgcn_mfma_f32_16x16x32_f16(      \
            af[2 * ((G) >> 2) + 1], BUF##7, acc[((G) & 3) * 4 + 3], 0, 0, 0); \
    }

#define STEPL(BUF, G, VM, GN)                                                 \
    asm volatile("s_waitcnt vmcnt(" VM ")" ::: "memory");                     \
    SCHED0();                                                                 \
    BMFMA(BUF, G);                                                            \
    BLOAD(BUF, GN);                                                           \
    SCHED0();

#define STEPN(BUF, G, VM)                                                     \
    asm volatile("s_waitcnt vmcnt(" VM ")" ::: "memory");                     \
    SCHED0();                                                                 \
    BMFMA(BUF, G);                                                            \
    SCHED0();

    // prologue: 3 batches in flight
    BLOAD(bA, 0);
    BLOAD(bB, 1);
    BLOAD(bC, 2);
    STEPL(bA, 0,  "16", 3);
    STEPL(bB, 1,  "16", 4);
    STEPL(bC, 2,  "16", 5);
    STEPL(bA, 3,  "16", 6);
    STEPL(bB, 4,  "16", 7);
    STEPL(bC, 5,  "16", 8);
    STEPL(bA, 6,  "16", 9);
    STEPL(bB, 7,  "16", 10);
    STEPL(bC, 8,  "16", 11);
    STEPL(bA, 9,  "16", 12);
    STEPL(bB, 10, "16", 13);
    STEPL(bC, 11, "16", 14);
    STEPL(bA, 12, "16", 15);
    STEPN(bB, 13, "16");
    STEPN(bC, 14, "8");
    STEPN(bA, 15, "0");

    // ---- partial row norms (rows lane-private: row = row0 + l15) ----
    ssq += __shfl_xor(ssq, 16, 64);
    ssq += __shfl_xor(ssq, 32, 64);
    if (lane < 16) nsq[wid][l15] = ssq;

    // ---- 2-round LDS reduction of the 4 partial acc sets ----
    if (wid == 1)
#pragma unroll
        for (int j = 0; j < 16; ++j) red[0][j][lane] = acc[j];
    if (wid == 3)
#pragma unroll
        for (int j = 0; j < 16; ++j) red[1][j][lane] = acc[j];
    __syncthreads();
    if (wid == 0)
#pragma unroll
        for (int j = 0; j < 16; ++j) acc[j] += red[0][j][lane];
    if (wid == 2)
#pragma unroll
        for (int j = 0; j < 16; ++j) {
            acc[j] += red[1][j][lane];
            red[1][j][lane] = acc[j];
        }
    if (wid == 1 && lane < 16) {     // finalize norms on an idle wave
        const float s = nsq[0][lane] + nsq[1][lane] + nsq[2][lane] + nsq[3][lane];
        const float n = sqrtf(s) + 1.1920929e-07f;
        const int grow = row0 + lane;
        if (grow < BATCH) xn[grow] = n; else wn[grow - BATCH] = n;
    }
    __syncthreads();
    if (wid == 0)
#pragma unroll
        for (int j = 0; j < 16; ++j) {
            acc[j] += red[1][j][lane];
            red[0][j][lane] = acc[j];
        }
    __syncthreads();

    // ---- distributed epilogue: wave w owns acc slots s = w*4 .. w*4+3,
    //      which hold column-block jc = (s + roff) & 15 ----
    f32x4 facc[4];
#pragma unroll
    for (int jj = 0; jj < 4; ++jj) facc[jj] = red[0][wid * 4 + jj][lane];

#pragma unroll
    for (int jj = 0; jj < 4; ++jj) {
        const int j = (wid * 4 + jj + roff) & 15;    // actual column block
#pragma unroll
        for (int q = 0; q < 4; ++q) {
            const float v = facc[jj][q];
            int bit = (v >= 0.0f) ? 1 : 0;
            u64 fl = __ballot(fabsf(v) < NZ_THRESH);
            while (fl) {   // rare (~4/wave): whole wave re-dots in fp64
                const int src = __ffsll((long long)fl) - 1;
                fl &= fl - 1;
                const int lrow = ((src >> 4) << 2) + q;
                const int col  = j * 16 + (src & 15);
                const float* xr = Asrc + (size_t)lrow * INF + lane * 16;
                const float* pr = Pf + (size_t)col * INF + lane * 16;
                double s = 0.0;
#pragma unroll
                for (int c4 = 0; c4 < 4; ++c4) {
                    float4 xa = *(const float4*)(xr + c4 * 4);
                    float4 pa = *(const float4*)(pr + c4 * 4);
                    s += (double)xa.x * pa.x + (double)xa.y * pa.y +
                         (double)xa.z * pa.z + (double)xa.w * pa.w;
                }
#pragma unroll
                for (int off = 32; off; off >>= 1) s += __shfl_xor(s, off, 64);
                if (lane == src) bit = (s >= 0.0) ? 1 : 0;
            }
            const u64 b = __ballot(bit != 0);
            if (l15 == 0)
                sw[l4 * 4 + q][j] = (u16)(b >> (l4 * 16));
        }
    }
    __syncthreads();
    if (t < 64) {
        const int r = t >> 2, w = t & 3;
        const u64 val = *(const u64*)&sw[r][w * 4];
        const int grow = row0 + r;
        if (grow < BATCH) cx[(size_t)grow * 4 + w] = val;
        else              cw[(size_t)(grow - BATCH) * 4 + w] = val;
    }
}

// ---------------------------------------------------------------------------
// out[b][m] = xn[b] * wn[m] * cos(pi * popc / 256).  Output stores are
// non-temporal (64 MB write-once stream; keep it out of L2).
// ---------------------------------------------------------------------------
__global__ __launch_bounds__(256) void popc_out(const u64* __restrict__ cx,
                                                const u64* __restrict__ cw,
                                                const float* __restrict__ xn,
                                                const float* __restrict__ wn,
                                                float* __restrict__ out) {
    __shared__ float lut[257];
    __shared__ u64 cxs[64][4];
    __shared__ float xns[64];
    const int t = threadIdx.x;

    lut[t] = (float)cos((double)t * (3.14159265358979323846 / 256.0));
    if (t == 0) lut[256] = -1.0f;

    const int r0 = blockIdx.x * 64;
    cxs[t >> 2][t & 3] = cx[(size_t)r0 * 4 + t];
    if (t < 64) xns[t] = xn[r0 + t];

    const ulonglong4* cwv4 = (const ulonglong4*)cw;
    ulonglong4 c0 = cwv4[4 * t + 0];
    ulonglong4 c1 = cwv4[4 * t + 1];
    ulonglong4 c2 = cwv4[4 * t + 2];
    ulonglong4 c3 = cwv4[4 * t + 3];
    float4 wnr = ((const float4*)wn)[t];

    __syncthreads();

    f32x4* outv = (f32x4*)out;
    const size_t obase = (size_t)r0 * (OUTF / 4) + t;
#pragma unroll 4
    for (int r = 0; r < 64; ++r) {
        const u64 a0 = cxs[r][0], a1 = cxs[r][1], a2 = cxs[r][2], a3 = cxs[r][3];
        const float sx = xns[r];
        f32x4 o;
        o[0] = sx * wnr.x * lut[__popcll(a0 ^ c0.x) + __popcll(a1 ^ c0.y) +
                                __popcll(a2 ^ c0.z) + __popcll(a3 ^ c0.w)];
        o[1] = sx * wnr.y * lut[__popcll(a0 ^ c1.x) + __popcll(a1 ^ c1.y) +
                                __popcll(a2 ^ c1.z) + __popcll(a3 ^ c1.w)];
        o[2] = sx * wnr.z * lut[__popcll(a0 ^ c2.x) + __popcll(a1 ^ c2.y) +
                                __popcll(a2 ^ c2.z) + __popcll(a3 ^ c2.w)];
        o[3] = sx * wnr.w * lut[__popcll(a0 ^ c3.x) + __popcll(a1 ^ c3.y) +
                                __popcll(a2 ^ c3.z) + __popcll(a3 ^ c3.w)];
        __builtin_nontemporal_store(o, &outv[obase + (size_t)r * (OUTF / 4)]);
    }
}

extern "C" void kernel_launch(void* const* d_in, const int* in_sizes, int n_in,
                              void* d_out, int out_size, void* d_ws, size_t ws_size,
                              hipStream_t stream) {
    const float* x = (const float*)d_in[0];
    const float* w = (const float*)d_in[1];
    const float* P = (const float*)d_in[2];
    float* out = (float*)d_out;

    char* ws = (char*)d_ws;
    f16*  Bf = (f16*)ws;                         // +0        (524288 B)
    u64*  cx = (u64*)(ws + 524288);              // +524288   (524288 B)
    u64*  cw = (u64*)(ws + 1048576);             // +1048576  (32768 B)
    float* xn = (float*)(ws + 1081344);          // +1081344  (65536 B)
    float* wn = (float*)(ws + 1146880);          // +1146880  (4096 B)

    prep_p<<<16, 256, 0, stream>>>(P, Bf);

    gemm_signs<<<MTOT / 16, 256, 0, stream>>>(x, w, Bf, P, cx, cw, xn, wn);

    popc_out<<<BATCH / 64, 256, 0, stream>>>(cx, cw, xn, wn, out);
}